// Round 3
// baseline (98.426 us; speedup 1.0000x reference)
//
#include <hip/hip_runtime.h>
#include <hip/hip_bf16.h>

// Problem constants
#define BB 8
#define CC 64
#define OO 64
#define HH 128
#define WWI 128
#define HWSZ (HH * WWI)     // 16384
#define KK 9                // 3x3 taps
#define II (KK * CC)        // 576

typedef __attribute__((ext_vector_type(8))) short bf16x8;
typedef __attribute__((ext_vector_type(4))) float f32x4;
typedef __attribute__((ext_vector_type(4))) unsigned int uint4v;

__device__ __forceinline__ int iclamp(int v, int lo, int hi) {
    return v < lo ? lo : (v > hi ? hi : v);
}
__device__ __forceinline__ unsigned short f2bf(float f) {  // RNE
    unsigned u = __float_as_uint(f);
    return (unsigned short)((u + 0x7fffu + ((u >> 16) & 1u)) >> 16);
}
// bf16 pair unpack: low element = u<<16, high element = u & 0xffff0000
__device__ __forceinline__ float bfl(unsigned u) { return __uint_as_float(u << 16); }
__device__ __forceinline__ float bfh(unsigned u) { return __uint_as_float(u & 0xffff0000u); }

// ---------- prep 1: x [B][C][H][W] f32 -> xt [B][H][W][C] bf16 (LDS transpose)
__global__ __launch_bounds__(256) void prep_xt(const float* __restrict__ x,
                                               unsigned short* __restrict__ xt) {
    __shared__ float tile[64][65];
    const int b = blockIdx.y;
    const int p0 = blockIdx.x * 64;
    const int t = threadIdx.x;
    const int a = t >> 6;   // 0..3
    const int q = t & 63;   // 0..63
    const float* xb = x + (size_t)b * CC * HWSZ + p0;
#pragma unroll
    for (int r = 0; r < 16; ++r) {
        int c = r * 4 + a;
        tile[c][q] = xb[(size_t)c * HWSZ + q];   // coalesced read
    }
    __syncthreads();
    unsigned short* xo = xt + ((size_t)b * HWSZ + p0) * CC;
#pragma unroll
    for (int r = 0; r < 16; ++r) {
        int pl = r * 4 + a;
        xo[(size_t)pl * CC + q] = f2bf(tile[q][pl]);  // coalesced 2B x 64 write
    }
}

// ---------- prep 2: W -> fragment-ordered bf16 layout
// waf[slab][lane][j], slab = (k*2+kc)*4 + m, value =
//   W.flat[o = m*16+(lane&15)][i = k*64 + kc*32 + (lane>>4)*8 + j]
// so a wave's A-frag load for (k,kc,m) is one contiguous 1 KB read.
__global__ void prep_waf(const float* __restrict__ w, unsigned short* __restrict__ waf) {
    int tid = blockIdx.x * 256 + threadIdx.x;
    if (tid < 72 * 512) {
        int slab = tid >> 9;           // 0..71
        int r = tid & 511;
        int l = r >> 3, j = r & 7;
        int m = slab & 3;
        int kc = (slab >> 2) & 1;
        int k = slab >> 3;
        int o = m * 16 + (l & 15);
        int i = k * 64 + kc * 32 + (l >> 4) * 8 + j;
        waf[tid] = f2bf(w[(size_t)o * II + i]);
    }
}

// ---------- main: wave-independent, no LDS, no barriers.
// Each wave: 16 pixels x 64 outputs. Lane samples its own B-fragment:
// px = lane&15, channel chunks at (lane>>4)*8 and 32+(lane>>4)*8.
__global__ __launch_bounds__(256) void deform_mfma2(
        const unsigned short* __restrict__ xt,   // [B][H][W][C] bf16
        const float* __restrict__ off,           // [B][2K][H][W]
        const unsigned short* __restrict__ waf,  // frag-ordered W, bf16
        const float* __restrict__ bias,          // [O]
        float* __restrict__ out) {               // [B][O][H][W]
    const int b = blockIdx.y;
    const int t = threadIdx.x;
    const int wave = t >> 6;
    const int lane = t & 63;
    const int px = lane & 15;
    const int hi = lane >> 4;            // 0..3
    const int p0 = blockIdx.x * 64 + wave * 16;
    const int p = p0 + px;
    const int wo = p & (WWI - 1);
    const int ho = p >> 7;

    const float* offp = off + (size_t)b * 2 * KK * HWSZ + p;
    const unsigned short* xtb = xt + (size_t)b * HWSZ * CC;

    // preload all tap offsets (kills the per-tap serial load->addr chain)
    float gxs[KK], gys[KK];
#pragma unroll
    for (int k = 0; k < KK; ++k) {
        gxs[k] = offp[(size_t)(2 * k + 0) * HWSZ] + (float)wo;  // padded coords
        gys[k] = offp[(size_t)(2 * k + 1) * HWSZ] + (float)ho;
    }

    f32x4 acc[4];
#pragma unroll
    for (int m = 0; m < 4; ++m) acc[m] = (f32x4)(0.0f);

    const int c0 = hi * 8;          // channel base, kc=0 chunk
    const int c1 = 32 + hi * 8;     // channel base, kc=1 chunk

#pragma unroll 1
    for (int k = 0; k < KK; ++k) {
        const float gx = gxs[k], gy = gys[k];
        const float fxf = floorf(gx), fyf = floorf(gy);
        const float fx = gx - fxf, fy = gy - fyf;
        const int ux0 = (int)fxf - 1, ux1 = (int)fxf;      // unpadded corner coords
        const int uy0 = (int)fyf - 1, uy1 = (int)fyf;
        const float vx0 = ((unsigned)ux0 < (unsigned)WWI) ? 1.0f : 0.0f;
        const float vx1 = ((unsigned)ux1 < (unsigned)WWI) ? 1.0f : 0.0f;
        const float vy0 = ((unsigned)uy0 < (unsigned)HH) ? 1.0f : 0.0f;
        const float vy1 = ((unsigned)uy1 < (unsigned)HH) ? 1.0f : 0.0f;
        const float w00 = (1.0f - fy) * (1.0f - fx) * vy0 * vx0;
        const float w01 = (1.0f - fy) * fx          * vy0 * vx1;
        const float w10 = fy          * (1.0f - fx) * vy1 * vx0;
        const float w11 = fy          * fx          * vy1 * vx1;
        const int cx0 = iclamp(ux0, 0, WWI - 1), cx1 = iclamp(ux1, 0, WWI - 1);
        const int cy0 = iclamp(uy0, 0, HH - 1),  cy1 = iclamp(uy1, 0, HH - 1);

        const unsigned short* r00 = xtb + (size_t)(cy0 * WWI + cx0) * CC;
        const unsigned short* r01 = xtb + (size_t)(cy0 * WWI + cx1) * CC;
        const unsigned short* r10 = xtb + (size_t)(cy1 * WWI + cx0) * CC;
        const unsigned short* r11 = xtb + (size_t)(cy1 * WWI + cx1) * CC;

        // 8 x 16B corner loads (this lane's two channel chunks)
        const uint4v A0 = *(const uint4v*)(r00 + c0), A1 = *(const uint4v*)(r00 + c1);
        const uint4v B0 = *(const uint4v*)(r01 + c0), B1 = *(const uint4v*)(r01 + c1);
        const uint4v C0 = *(const uint4v*)(r10 + c0), C1 = *(const uint4v*)(r10 + c1);
        const uint4v D0 = *(const uint4v*)(r11 + c0), D1 = *(const uint4v*)(r11 + c1);

        // 8 x 16B A-frag loads, wave-wide contiguous 1 KB each, L2-resident
        const unsigned short* wk = waf + (size_t)k * 8 * 512 + lane * 8;
        bf16x8 af[8];
#pragma unroll
        for (int q = 0; q < 8; ++q) af[q] = *(const bf16x8*)(wk + (size_t)q * 512);

        // interpolate -> this lane's B-fragments (registers, no LDS)
        bf16x8 bf0, bf1;
        {
            __hip_bfloat162* rp0 = (__hip_bfloat162*)&bf0;
            __hip_bfloat162* rp1 = (__hip_bfloat162*)&bf1;
#pragma unroll
            for (int i = 0; i < 4; ++i) {
                float vlo = w00 * bfl(A0[i]) + w01 * bfl(B0[i])
                          + w10 * bfl(C0[i]) + w11 * bfl(D0[i]);
                float vhi = w00 * bfh(A0[i]) + w01 * bfh(B0[i])
                          + w10 * bfh(C0[i]) + w11 * bfh(D0[i]);
                rp0[i] = __hip_bfloat162{__float2bfloat16(vlo), __float2bfloat16(vhi)};
                float ulo = w00 * bfl(A1[i]) + w01 * bfl(B1[i])
                          + w10 * bfl(C1[i]) + w11 * bfl(D1[i]);
                float uhi = w00 * bfh(A1[i]) + w01 * bfh(B1[i])
                          + w10 * bfh(C1[i]) + w11 * bfh(D1[i]);
                rp1[i] = __hip_bfloat162{__float2bfloat16(ulo), __float2bfloat16(uhi)};
            }
        }

#pragma unroll
        for (int m = 0; m < 4; ++m)
            acc[m] = __builtin_amdgcn_mfma_f32_16x16x32_bf16(af[m], bf0, acc[m], 0, 0, 0);
#pragma unroll
        for (int m = 0; m < 4; ++m)
            acc[m] = __builtin_amdgcn_mfma_f32_16x16x32_bf16(af[4 + m], bf1, acc[m], 0, 0, 0);
    }

    // epilogue: D layout col = lane&15 (px), row = hi*4 + j within each m-tile
    float* outb = out + (size_t)b * OO * HWSZ + p0 + px;
#pragma unroll
    for (int m = 0; m < 4; ++m) {
        const int ob = m * 16 + hi * 4;
        const float4 bs = *(const float4*)(bias + ob);
#pragma unroll
        for (int j = 0; j < 4; ++j) {
            outb[(size_t)(ob + j) * HWSZ] = acc[m][j] + ((const float*)&bs)[j];
        }
    }
}

// ---------- fallback (round-1 fp32 path, used only if ws too small) ----------
__global__ __launch_bounds__(256) void deform_conv_fallback(
        const float* __restrict__ x, const float* __restrict__ off,
        const float* __restrict__ wmat, const float* __restrict__ bias,
        float* __restrict__ out) {
    const int b = blockIdx.y;
    const int p = blockIdx.x * 256 + threadIdx.x;
    const int wo = p & (WWI - 1);
    const int ho = p >> 7;
    const float* xb = x + (size_t)b * CC * HWSZ;
    const float* offb = off + (size_t)b * 2 * KK * HWSZ + p;
    float acc[OO];
#pragma unroll
    for (int o = 0; o < OO; ++o) acc[o] = 0.0f;
#pragma unroll 1
    for (int k = 0; k < KK; ++k) {
        const float gx = offb[(size_t)(2 * k + 0) * HWSZ] + (float)wo;
        const float gy = offb[(size_t)(2 * k + 1) * HWSZ] + (float)ho;
        const float fxf = floorf(gx), fyf = floorf(gy);
        const float fx = gx - fxf, fy = gy - fyf;
        const int ux0 = (int)fxf - 1, ux1 = (int)fxf;
        const int uy0 = (int)fyf - 1, uy1 = (int)fyf;
        const float vx0 = ((unsigned)ux0 < (unsigned)WWI) ? 1.0f : 0.0f;
        const float vx1 = ((unsigned)ux1 < (unsigned)WWI) ? 1.0f : 0.0f;
        const float vy0 = ((unsigned)uy0 < (unsigned)HH) ? 1.0f : 0.0f;
        const float vy1 = ((unsigned)uy1 < (unsigned)HH) ? 1.0f : 0.0f;
        const float w00 = (1.0f - fy) * (1.0f - fx) * vy0 * vx0;
        const float w01 = (1.0f - fy) * fx * vy0 * vx1;
        const float w10 = fy * (1.0f - fx) * vy1 * vx0;
        const float w11 = fy * fx * vy1 * vx1;
        const int cx0 = iclamp(ux0, 0, WWI - 1), cx1 = iclamp(ux1, 0, WWI - 1);
        const int cy0 = iclamp(uy0, 0, HH - 1), cy1 = iclamp(uy1, 0, HH - 1);
        const int i00 = cy0 * WWI + cx0, i01 = cy0 * WWI + cx1;
        const int i10 = cy1 * WWI + cx0, i11 = cy1 * WWI + cx1;
#pragma unroll 4
        for (int c = 0; c < CC; ++c) {
            const float* xc = xb + (size_t)c * HWSZ;
            const float v = w00 * xc[i00] + w01 * xc[i01] + w10 * xc[i10] + w11 * xc[i11];
            const float* wrow = wmat + (size_t)(k * CC + c);
#pragma unroll
            for (int o = 0; o < OO; ++o) acc[o] = fmaf(wrow[(size_t)o * II], v, acc[o]);
        }
    }
    float* outb = out + (size_t)b * OO * HWSZ + p;
#pragma unroll
    for (int o = 0; o < OO; ++o) outb[(size_t)o * HWSZ] = acc[o] + bias[o];
}

extern "C" void kernel_launch(void* const* d_in, const int* in_sizes, int n_in,
                              void* d_out, int out_size, void* d_ws, size_t ws_size,
                              hipStream_t stream) {
    const float* x    = (const float*)d_in[0];
    const float* off  = (const float*)d_in[1];
    const float* w    = (const float*)d_in[2];
    const float* bias = (const float*)d_in[3];
    float* out = (float*)d_out;

    const size_t xt_bytes  = (size_t)BB * HWSZ * CC * sizeof(unsigned short); // 16.78 MB
    const size_t waf_bytes = (size_t)72 * 512 * sizeof(unsigned short);       // 73728 B

    if (ws_size >= xt_bytes + waf_bytes) {
        unsigned short* xt  = (unsigned short*)d_ws;
        unsigned short* wfp = (unsigned short*)((char*)d_ws + xt_bytes);
        prep_xt<<<dim3(HWSZ / 64, BB), 256, 0, stream>>>(x, xt);
        prep_waf<<<(72 * 512 + 255) / 256, 256, 0, stream>>>(w, wfp);
        deform_mfma2<<<dim3(HWSZ / 64, BB), 256, 0, stream>>>(xt, off, wfp, bias, out);
    } else {
        deform_conv_fallback<<<dim3(HWSZ / 256, BB), 256, 0, stream>>>(x, off, w, bias, out);
    }
}

// Round 4
// 97.198 us; speedup vs baseline: 1.0126x; 1.0126x over previous
//
#include <hip/hip_runtime.h>
#include <hip/hip_bf16.h>

// Problem constants
#define BB 8
#define CC 64
#define OO 64
#define HH 128
#define WWI 128
#define HWSZ (HH * WWI)     // 16384
#define KK 9                // 3x3 taps
#define II (KK * CC)        // 576

typedef __attribute__((ext_vector_type(8))) short bf16x8;
typedef __attribute__((ext_vector_type(4))) float f32x4;
typedef __attribute__((ext_vector_type(4))) unsigned int uint4v;

__device__ __forceinline__ int iclamp(int v, int lo, int hi) {
    return v < lo ? lo : (v > hi ? hi : v);
}
__device__ __forceinline__ unsigned short f2bf(float f) {  // RNE
    unsigned u = __float_as_uint(f);
    return (unsigned short)((u + 0x7fffu + ((u >> 16) & 1u)) >> 16);
}
// bf16 pair unpack: low element = u<<16, high element = u & 0xffff0000
__device__ __forceinline__ float bfl(unsigned u) { return __uint_as_float(u << 16); }
__device__ __forceinline__ float bfh(unsigned u) { return __uint_as_float(u & 0xffff0000u); }

// ---------- prep 1: x [B][C][H][W] f32 -> xt [B][H][W][C] bf16 (LDS transpose)
// 1-D grid, XCD-swizzled: b = blk&7 so image b is written from XCD b (its L2
// then holds the 2.1 MB slab for the main kernel, which uses the same map).
__global__ __launch_bounds__(256) void prep_xt(const float* __restrict__ x,
                                               unsigned short* __restrict__ xt) {
    __shared__ float tile[64][65];
    const int blk = blockIdx.x;
    const int b = blk & 7;
    const int p0 = (blk >> 3) * 64;
    const int t = threadIdx.x;
    const int a = t >> 6;   // 0..3
    const int q = t & 63;   // 0..63
    const float* xb = x + (size_t)b * CC * HWSZ + p0;
#pragma unroll
    for (int r = 0; r < 16; ++r) {
        int c = r * 4 + a;
        tile[c][q] = xb[(size_t)c * HWSZ + q];   // coalesced read
    }
    __syncthreads();
    unsigned short* xo = xt + ((size_t)b * HWSZ + p0) * CC;
#pragma unroll
    for (int r = 0; r < 16; ++r) {
        int pl = r * 4 + a;
        xo[(size_t)pl * CC + q] = f2bf(tile[q][pl]);  // coalesced 2B x 64 write
    }
}

// ---------- prep 2: W -> fragment-ordered bf16 layout
// waf[slab][lane][j], slab = (k*2+kc)*4 + m, value =
//   W.flat[o = m*16+(lane&15)][i = k*64 + kc*32 + (lane>>4)*8 + j]
__global__ void prep_waf(const float* __restrict__ w, unsigned short* __restrict__ waf) {
    int tid = blockIdx.x * 256 + threadIdx.x;
    if (tid < 72 * 512) {
        int slab = tid >> 9;           // 0..71
        int r = tid & 511;
        int l = r >> 3, j = r & 7;
        int m = slab & 3;
        int kc = (slab >> 2) & 1;
        int k = slab >> 3;
        int o = m * 16 + (l & 15);
        int i = k * 64 + kc * 32 + (l >> 4) * 8 + j;
        waf[tid] = f2bf(w[(size_t)o * II + i]);
    }
}

// pipeline payload: 8 corner vectors + folded bilinear weights
struct Samp {
    uint4v A0, A1, B0, B1, C0, C1, D0, D1;
    float w00, w01, w10, w11;
};

// ---------- main: wave-independent, no LDS, depth-2 register pipeline.
__global__ __launch_bounds__(256, 4) void deform_mfma3(
        const unsigned short* __restrict__ xt,   // [B][H][W][C] bf16
        const float* __restrict__ off,           // [B][2K][H][W]
        const unsigned short* __restrict__ waf,  // frag-ordered W, bf16
        const float* __restrict__ bias,          // [O]
        float* __restrict__ out) {               // [B][O][H][W]
    const int blk = blockIdx.x;
    const int b = blk & 7;                    // XCD-ownership: image b on XCD b
    const int t = threadIdx.x;
    const int wave = t >> 6;
    const int lane = t & 63;
    const int px = lane & 15;
    const int hi = lane >> 4;                 // 0..3
    const int p0 = (blk >> 3) * 64 + wave * 16;
    const int p = p0 + px;
    const int wo = p & (WWI - 1);
    const int ho = p >> 7;

    const float* offp = off + (size_t)b * 2 * KK * HWSZ + p;
    const unsigned short* xtb = xt + (size_t)b * HWSZ * CC;
    const int c0 = hi * 8;                    // channel base, kc=0 chunk
    const int c1 = 32 + hi * 8;               // channel base, kc=1 chunk

    // load offsets for tap k (2 loads, no use here -> stays in flight)
    auto loadOff = [&](int k) -> float2 {
        return make_float2(offp[(size_t)(2 * k + 0) * HWSZ],
                           offp[(size_t)(2 * k + 1) * HWSZ]);
    };

    // compute weights + issue 8 corner loads for one tap
    auto prepSample = [&](float2 o) -> Samp {
        Samp s;
        const float gx = o.x + (float)wo;     // padded coords
        const float gy = o.y + (float)ho;
        const float fxf = floorf(gx), fyf = floorf(gy);
        const float fx = gx - fxf, fy = gy - fyf;
        const int ux0 = (int)fxf - 1, ux1 = (int)fxf;      // unpadded corners
        const int uy0 = (int)fyf - 1, uy1 = (int)fyf;
        const float vx0 = ((unsigned)ux0 < (unsigned)WWI) ? 1.0f : 0.0f;
        const float vx1 = ((unsigned)ux1 < (unsigned)WWI) ? 1.0f : 0.0f;
        const float vy0 = ((unsigned)uy0 < (unsigned)HH) ? 1.0f : 0.0f;
        const float vy1 = ((unsigned)uy1 < (unsigned)HH) ? 1.0f : 0.0f;
        s.w00 = (1.0f - fy) * (1.0f - fx) * vy0 * vx0;
        s.w01 = (1.0f - fy) * fx          * vy0 * vx1;
        s.w10 = fy          * (1.0f - fx) * vy1 * vx0;
        s.w11 = fy          * fx          * vy1 * vx1;
        const int cx0 = iclamp(ux0, 0, WWI - 1), cx1 = iclamp(ux1, 0, WWI - 1);
        const int cy0 = iclamp(uy0, 0, HH - 1),  cy1 = iclamp(uy1, 0, HH - 1);
        const unsigned short* r00 = xtb + (size_t)(cy0 * WWI + cx0) * CC;
        const unsigned short* r01 = xtb + (size_t)(cy0 * WWI + cx1) * CC;
        const unsigned short* r10 = xtb + (size_t)(cy1 * WWI + cx0) * CC;
        const unsigned short* r11 = xtb + (size_t)(cy1 * WWI + cx1) * CC;
        s.A0 = *(const uint4v*)(r00 + c0);  s.A1 = *(const uint4v*)(r00 + c1);
        s.B0 = *(const uint4v*)(r01 + c0);  s.B1 = *(const uint4v*)(r01 + c1);
        s.C0 = *(const uint4v*)(r10 + c0);  s.C1 = *(const uint4v*)(r10 + c1);
        s.D0 = *(const uint4v*)(r11 + c0);  s.D1 = *(const uint4v*)(r11 + c1);
        return s;
    };

    f32x4 acc[4];
#pragma unroll
    for (int m = 0; m < 4; ++m) acc[m] = (f32x4)(0.0f);

    // consume one staged tap: waf frag loads, interpolate, 8 MFMA
    auto process = [&](int k, const Samp& s) {
        const unsigned short* wk = waf + (size_t)k * 8 * 512 + lane * 8;
        bf16x8 af[8];
#pragma unroll
        for (int q = 0; q < 8; ++q) af[q] = *(const bf16x8*)(wk + (size_t)q * 512);

        bf16x8 bf0, bf1;
        __hip_bfloat162* rp0 = (__hip_bfloat162*)&bf0;
        __hip_bfloat162* rp1 = (__hip_bfloat162*)&bf1;
#pragma unroll
        for (int i = 0; i < 4; ++i) {
            float vlo = s.w00 * bfl(s.A0[i]) + s.w01 * bfl(s.B0[i])
                      + s.w10 * bfl(s.C0[i]) + s.w11 * bfl(s.D0[i]);
            float vhi = s.w00 * bfh(s.A0[i]) + s.w01 * bfh(s.B0[i])
                      + s.w10 * bfh(s.C0[i]) + s.w11 * bfh(s.D0[i]);
            rp0[i] = __hip_bfloat162{__float2bfloat16(vlo), __float2bfloat16(vhi)};
            float ulo = s.w00 * bfl(s.A1[i]) + s.w01 * bfl(s.B1[i])
                      + s.w10 * bfl(s.C1[i]) + s.w11 * bfl(s.D1[i]);
            float uhi = s.w00 * bfh(s.A1[i]) + s.w01 * bfh(s.B1[i])
                      + s.w10 * bfh(s.C1[i]) + s.w11 * bfh(s.D1[i]);
            rp1[i] = __hip_bfloat162{__float2bfloat16(ulo), __float2bfloat16(uhi)};
        }
#pragma unroll
        for (int m = 0; m < 4; ++m)
            acc[m] = __builtin_amdgcn_mfma_f32_16x16x32_bf16(af[m], bf0, acc[m], 0, 0, 0);
#pragma unroll
        for (int m = 0; m < 4; ++m)
            acc[m] = __builtin_amdgcn_mfma_f32_16x16x32_bf16(af[4 + m], bf1, acc[m], 0, 0, 0);
    };

    // ---- depth-2 pipeline: off[k+2] load || corners[k+1] load || process k ----
    float2 oA = loadOff(0);
    Samp cur = prepSample(oA);           // tap 0 in flight
    float2 oB = loadOff(1);
#pragma unroll 1
    for (int k = 0; k < KK - 1; ++k) {
        Samp nxt = prepSample(oB);       // issue loads for tap k+1 (oB arrived)
        float2 oN = oB;
        if (k + 2 < KK) oN = loadOff(k + 2);
        process(k, cur);                 // consume tap k (waits arrive here)
        cur = nxt;
        oB = oN;
    }
    process(KK - 1, cur);

    // epilogue: D layout col = lane&15 (px), row = hi*4 + j within each m-tile
    float* outb = out + (size_t)b * OO * HWSZ + p0 + px;
#pragma unroll
    for (int m = 0; m < 4; ++m) {
        const int ob = m * 16 + hi * 4;
        const float4 bs = *(const float4*)(bias + ob);
#pragma unroll
        for (int j = 0; j < 4; ++j) {
            outb[(size_t)(ob + j) * HWSZ] = acc[m][j] + ((const float*)&bs)[j];
        }
    }
}

// ---------- fallback (round-1 fp32 path, used only if ws too small) ----------
__global__ __launch_bounds__(256) void deform_conv_fallback(
        const float* __restrict__ x, const float* __restrict__ off,
        const float* __restrict__ wmat, const float* __restrict__ bias,
        float* __restrict__ out) {
    const int b = blockIdx.y;
    const int p = blockIdx.x * 256 + threadIdx.x;
    const int wo = p & (WWI - 1);
    const int ho = p >> 7;
    const float* xb = x + (size_t)b * CC * HWSZ;
    const float* offb = off + (size_t)b * 2 * KK * HWSZ + p;
    float acc[OO];
#pragma unroll
    for (int o = 0; o < OO; ++o) acc[o] = 0.0f;
#pragma unroll 1
    for (int k = 0; k < KK; ++k) {
        const float gx = offb[(size_t)(2 * k + 0) * HWSZ] + (float)wo;
        const float gy = offb[(size_t)(2 * k + 1) * HWSZ] + (float)ho;
        const float fxf = floorf(gx), fyf = floorf(gy);
        const float fx = gx - fxf, fy = gy - fyf;
        const int ux0 = (int)fxf - 1, ux1 = (int)fxf;
        const int uy0 = (int)fyf - 1, uy1 = (int)fyf;
        const float vx0 = ((unsigned)ux0 < (unsigned)WWI) ? 1.0f : 0.0f;
        const float vx1 = ((unsigned)ux1 < (unsigned)WWI) ? 1.0f : 0.0f;
        const float vy0 = ((unsigned)uy0 < (unsigned)HH) ? 1.0f : 0.0f;
        const float vy1 = ((unsigned)uy1 < (unsigned)HH) ? 1.0f : 0.0f;
        const float w00 = (1.0f - fy) * (1.0f - fx) * vy0 * vx0;
        const float w01 = (1.0f - fy) * fx * vy0 * vx1;
        const float w10 = fy * (1.0f - fx) * vy1 * vx0;
        const float w11 = fy * fx * vy1 * vx1;
        const int cx0 = iclamp(ux0, 0, WWI - 1), cx1 = iclamp(ux1, 0, WWI - 1);
        const int cy0 = iclamp(uy0, 0, HH - 1), cy1 = iclamp(uy1, 0, HH - 1);
        const int i00 = cy0 * WWI + cx0, i01 = cy0 * WWI + cx1;
        const int i10 = cy1 * WWI + cx0, i11 = cy1 * WWI + cx1;
#pragma unroll 4
        for (int c = 0; c < CC; ++c) {
            const float* xc = xb + (size_t)c * HWSZ;
            const float v = w00 * xc[i00] + w01 * xc[i01] + w10 * xc[i10] + w11 * xc[i11];
            const float* wrow = wmat + (size_t)(k * CC + c);
#pragma unroll
            for (int o = 0; o < OO; ++o) acc[o] = fmaf(wrow[(size_t)o * II], v, acc[o]);
        }
    }
    float* outb = out + (size_t)b * OO * HWSZ + p;
#pragma unroll
    for (int o = 0; o < OO; ++o) outb[(size_t)o * HWSZ] = acc[o] + bias[o];
}

extern "C" void kernel_launch(void* const* d_in, const int* in_sizes, int n_in,
                              void* d_out, int out_size, void* d_ws, size_t ws_size,
                              hipStream_t stream) {
    const float* x    = (const float*)d_in[0];
    const float* off  = (const float*)d_in[1];
    const float* w    = (const float*)d_in[2];
    const float* bias = (const float*)d_in[3];
    float* out = (float*)d_out;

    const size_t xt_bytes  = (size_t)BB * HWSZ * CC * sizeof(unsigned short); // 16.78 MB
    const size_t waf_bytes = (size_t)72 * 512 * sizeof(unsigned short);       // 73728 B

    if (ws_size >= xt_bytes + waf_bytes) {
        unsigned short* xt  = (unsigned short*)d_ws;
        unsigned short* wfp = (unsigned short*)((char*)d_ws + xt_bytes);
        prep_xt<<<dim3((HWSZ / 64) * BB), 256, 0, stream>>>(x, xt);
        prep_waf<<<(72 * 512 + 255) / 256, 256, 0, stream>>>(w, wfp);
        deform_mfma3<<<dim3((HWSZ / 64) * BB), 256, 0, stream>>>(xt, off, wfp, bias, out);
    } else {
        deform_conv_fallback<<<dim3(HWSZ / 256, BB), 256, 0, stream>>>(x, off, w, bias, out);
    }
}